// Round 5
// baseline (89.373 us; speedup 1.0000x reference)
//
#include <hip/hip_runtime.h>
#include <math.h>

#define LOG2E 1.4426950408889634f
#define LN2   0.6931471805599453f

static constexpr int M = 1024;
static constexpr int N = 65536;

typedef float v2f __attribute__((ext_vector_type(2)));

// packed f32 fma (VOP3P, gfx90a+/gfx950): d = a*b + c on both 32-bit halves
__device__ inline v2f pkfma(v2f a, v2f b, v2f c) {
    v2f d;
    asm("v_pk_fma_f32 %0, %1, %2, %3" : "=v"(d) : "v"(a), "v"(b), "v"(c));
    return d;
}

__device__ inline float wave_max64(float v) {
    #pragma unroll
    for (int o = 32; o > 0; o >>= 1) v = fmaxf(v, __shfl_xor(v, o));
    return v;
}
__device__ inline float wave_sum64(float v) {
    #pragma unroll
    for (int o = 32; o > 0; o >>= 1) v += __shfl_xor(v, o);
    return v;
}

// MEASUREMENT ROUND: kernel body is byte-identical to R4 (known passing,
// dur 74.0). kernel_launch launches it TWICE (idempotent: second launch
// recomputes the same out from the same inputs). dur_R5 - dur_R4 ~= one
// gm_all execution + one launch gap. This discriminates:
//   low-clock/issue-bound theory  -> dur ~100-106
//   harness-floor theory          -> dur ~76-81
__global__ __launch_bounds__(1024)
void gm_all(const float* __restrict__ sample,
            const float* __restrict__ mu,
            const float* __restrict__ A,
            const float* __restrict__ w,
            float* __restrict__ out) {
    __shared__ __align__(16) float coef[M*6];     // 24 KiB, pair-interleaved
    __shared__ float partial[16*256];             // 16 KiB

    const int t    = threadIdx.x;
    const int lane = t & 63;
    const int wv   = t >> 6;
    const int base = blockIdx.x * 256;

    // ---- issue all global loads up front ----
    float2 s[4];
    #pragma unroll
    for (int k = 0; k < 4; ++k)
        s[k] = ((const float2*)sample)[base + 64*k + lane];

    const float4 a4  = ((const float4*)A)[t];     // A00,A01,A10,A11 of comp t
    const float2 mu2 = ((const float2*)mu)[t];
    const float  wt  = w[t];

    float4 wq[4];                                 // all 1024 w's, 16/lane
    #pragma unroll
    for (int i = 0; i < 4; ++i)
        wq[i] = ((const float4*)w)[lane + 64*i];

    // ---- per-lane coefs for comp j = t ----
    const float g00 = a4.x*a4.x + a4.y*a4.y;
    const float g01 = a4.x*a4.z + a4.y*a4.w;
    const float g11 = a4.z*a4.z + a4.w*a4.w;
    const float gm0 = g00*mu2.x + g01*mu2.y;
    const float gm1 = g01*mu2.x + g11*mu2.y;
    const float mGm = gm0*mu2.x + gm1*mu2.y;
    const float det = g00*g11 - g01*g01;
    const float t2  = wt*LOG2E + 0.5f*__builtin_amdgcn_logf(det);

    // pair-interleaved: comp j -> pair p=j>>1, sub=j&1, coef c at p*12+2c+sub
    {
        float* c = coef + (t >> 1)*12 + (t & 1);
        c[0]  = t2 - LOG2E * mGm;
        c[2]  = LOG2E * 2.0f * gm0;
        c[4]  = LOG2E * 2.0f * gm1;
        c[6]  = -LOG2E * g00;
        c[8]  = -LOG2E * 2.0f * g01;
        c[10] = -LOG2E * g11;
    }

    // ---- w logsumexp (per-wave redundant; overlaps ds_write latency) ----
    float wmax = wq[0].x;
    #pragma unroll
    for (int i = 0; i < 4; ++i) {
        wmax = fmaxf(wmax, wq[i].x); wmax = fmaxf(wmax, wq[i].y);
        wmax = fmaxf(wmax, wq[i].z); wmax = fmaxf(wmax, wq[i].w);
    }
    wmax = wave_max64(wmax);
    float sw = 0.0f;
    #pragma unroll
    for (int i = 0; i < 4; ++i) {
        sw += __builtin_amdgcn_exp2f((wq[i].x - wmax)*LOG2E);
        sw += __builtin_amdgcn_exp2f((wq[i].y - wmax)*LOG2E);
        sw += __builtin_amdgcn_exp2f((wq[i].z - wmax)*LOG2E);
        sw += __builtin_amdgcn_exp2f((wq[i].w - wmax)*LOG2E);
    }
    sw = wave_sum64(sw);
    const float nlse = -(wmax*LOG2E + __builtin_amdgcn_logf(sw));   // -lse2

    // same-wave DS write -> read ordering; no __syncthreads needed
    asm volatile("s_waitcnt lgkmcnt(0)" ::: "memory");
    __builtin_amdgcn_sched_barrier(0);

    // ---- main loop: 32 pairs x 4 samples, pure VALU + broadcast ds_read ----
    v2f X[4], Y[4];
    #pragma unroll
    for (int k = 0; k < 4; ++k) {
        X[k] = (v2f){s[k].x, s[k].x};
        Y[k] = (v2f){s[k].y, s[k].y};
    }
    v2f acc[4] = {(v2f){0,0},(v2f){0,0},(v2f){0,0},(v2f){0,0}};

    const float4* cw = (const float4*)(coef + wv*64*6);   // wave's 32 pairs
    #pragma unroll 4
    for (int p = 0; p < 32; ++p) {
        const float4 q0 = cw[p*3 + 0];    // c0a c0b c1a c1b
        const float4 q1 = cw[p*3 + 1];    // c2a c2b c3a c3b
        const float4 q2 = cw[p*3 + 2];    // c4a c4b c5a c5b
        const v2f c0 = {q0.x, q0.y}, c1 = {q0.z, q0.w};
        const v2f c2 = {q1.x, q1.y}, c3 = {q1.z, q1.w};
        const v2f c4 = {q2.x, q2.y}, c5 = {q2.z, q2.w};
        #pragma unroll
        for (int k = 0; k < 4; ++k) {
            // q = c0 + x(c1 + c3x + c4y) + y(c2 + c5y): 5 pk_fma
            v2f u  = pkfma(c3, X[k], c1);
            u      = pkfma(c4, Y[k], u);
            v2f t3 = pkfma(c5, Y[k], c2);
            v2f v  = pkfma(u,  X[k], c0);
            v      = pkfma(t3, Y[k], v);
            // clamp: keep exp2 out of the underflow/denormal slow path
            const float ea = __builtin_amdgcn_exp2f(fmaxf(v.x, -126.0f));
            const float eb = __builtin_amdgcn_exp2f(fmaxf(v.y, -126.0f));
            acc[k] += (v2f){ea, eb};
        }
    }

    #pragma unroll
    for (int k = 0; k < 4; ++k)
        partial[wv*256 + 64*k + lane] = acc[k].x + acc[k].y;
    __syncthreads();

    if (t < 256) {
        float ssum = partial[t];
        #pragma unroll
        for (int i = 1; i < 16; ++i) ssum += partial[i*256 + t];
        out[base + t] = LN2 * (nlse + __builtin_amdgcn_logf(ssum));
    }
}

extern "C" void kernel_launch(void* const* d_in, const int* in_sizes, int n_in,
                              void* d_out, int out_size, void* d_ws, size_t ws_size,
                              hipStream_t stream) {
    const float* sample = (const float*)d_in[0];
    const float* mu     = (const float*)d_in[1];
    const float* A      = (const float*)d_in[2];
    const float* w      = (const float*)d_in[3];
    float* out = (float*)d_out;
    (void)in_sizes; (void)n_in; (void)out_size; (void)d_ws; (void)ws_size;

    // Double launch: idempotent (same inputs -> same out). Delta vs R4's
    // single launch measures one gm_all execution directly from dur_us.
    gm_all<<<256, 1024, 0, stream>>>(sample, mu, A, w, out);
    gm_all<<<256, 1024, 0, stream>>>(sample, mu, A, w, out);
}

// Round 6
// 70.216 us; speedup vs baseline: 1.2728x; 1.2728x over previous
//
#include <hip/hip_runtime.h>
#include <math.h>

#define LOG2E 1.4426950408889634f
#define LN2   0.6931471805599453f

static constexpr int M = 1024;
static constexpr int N = 65536;

typedef float v2f __attribute__((ext_vector_type(2)));

// packed f32 fma (VOP3P, gfx90a+/gfx950): d = a*b + c on both 32-bit halves
__device__ inline v2f pkfma(v2f a, v2f b, v2f c) {
    v2f d;
    asm("v_pk_fma_f32 %0, %1, %2, %3" : "=v"(d) : "v"(a), "v"(b), "v"(c));
    return d;
}

__device__ inline float wave_max64(float v) {
    #pragma unroll
    for (int o = 32; o > 0; o >>= 1) v = fmaxf(v, __shfl_xor(v, o));
    return v;
}
__device__ inline float wave_sum64(float v) {
    #pragma unroll
    for (int o = 32; o > 0; o >>= 1) v += __shfl_xor(v, o);
    return v;
}

// Single kernel: 256 blocks x 1024 threads (1 block/CU, 4 waves/SIMD).
// R5 measurement: gm_all ~= 13-15us (dur = 40us harness fill + kernel +
// ~19us harness dispatch overhead). Issue-bound; exp2 is ~55% of the
// issue budget and is irreducible (67.1M exps, no wave-uniform pruning
// possible for random sample/mu placement). R6 trims the reducible part:
//   - clamp removed (R4 proved denormal slow-path theory dead): -4 cyc/iter
//   - w-logsumexp prologue gated to waves 0-3 (only t<256 consume nlse)
__global__ __launch_bounds__(1024)
void gm_all(const float* __restrict__ sample,
            const float* __restrict__ mu,
            const float* __restrict__ A,
            const float* __restrict__ w,
            float* __restrict__ out) {
    __shared__ __align__(16) float coef[M*6];     // 24 KiB, pair-interleaved
    __shared__ float partial[16*256];             // 16 KiB

    const int t    = threadIdx.x;
    const int lane = t & 63;
    const int wv   = t >> 6;
    const int base = blockIdx.x * 256;

    // ---- issue global loads up front ----
    float2 s[4];
    #pragma unroll
    for (int k = 0; k < 4; ++k)
        s[k] = ((const float2*)sample)[base + 64*k + lane];

    const float4 a4  = ((const float4*)A)[t];     // A00,A01,A10,A11 of comp t
    const float2 mu2 = ((const float2*)mu)[t];
    const float  wt  = w[t];

    // ---- per-lane coefs for comp j = t ----
    const float g00 = a4.x*a4.x + a4.y*a4.y;
    const float g01 = a4.x*a4.z + a4.y*a4.w;
    const float g11 = a4.z*a4.z + a4.w*a4.w;
    const float gm0 = g00*mu2.x + g01*mu2.y;
    const float gm1 = g01*mu2.x + g11*mu2.y;
    const float mGm = gm0*mu2.x + gm1*mu2.y;
    const float det = g00*g11 - g01*g01;
    const float t2  = wt*LOG2E + 0.5f*__builtin_amdgcn_logf(det);

    // pair-interleaved: comp j -> pair p=j>>1, sub=j&1, coef c at p*12+2c+sub
    {
        float* c = coef + (t >> 1)*12 + (t & 1);
        c[0]  = t2 - LOG2E * mGm;
        c[2]  = LOG2E * 2.0f * gm0;
        c[4]  = LOG2E * 2.0f * gm1;
        c[6]  = -LOG2E * g00;
        c[8]  = -LOG2E * 2.0f * g01;
        c[10] = -LOG2E * g11;
    }

    // ---- w logsumexp: ONLY waves 0-3 (their threads t<256 use nlse) ----
    float nlse = 0.0f;
    if (wv < 4) {
        float4 wq[4];                             // all 1024 w's, 16/lane
        #pragma unroll
        for (int i = 0; i < 4; ++i)
            wq[i] = ((const float4*)w)[lane + 64*i];
        float wmax = wq[0].x;
        #pragma unroll
        for (int i = 0; i < 4; ++i) {
            wmax = fmaxf(wmax, wq[i].x); wmax = fmaxf(wmax, wq[i].y);
            wmax = fmaxf(wmax, wq[i].z); wmax = fmaxf(wmax, wq[i].w);
        }
        wmax = wave_max64(wmax);
        float sw = 0.0f;
        #pragma unroll
        for (int i = 0; i < 4; ++i) {
            sw += __builtin_amdgcn_exp2f((wq[i].x - wmax)*LOG2E);
            sw += __builtin_amdgcn_exp2f((wq[i].y - wmax)*LOG2E);
            sw += __builtin_amdgcn_exp2f((wq[i].z - wmax)*LOG2E);
            sw += __builtin_amdgcn_exp2f((wq[i].w - wmax)*LOG2E);
        }
        sw = wave_sum64(sw);
        nlse = -(wmax*LOG2E + __builtin_amdgcn_logf(sw));       // -lse2
    }

    // same-wave DS write -> read ordering; no __syncthreads needed
    asm volatile("s_waitcnt lgkmcnt(0)" ::: "memory");
    __builtin_amdgcn_sched_barrier(0);

    // ---- main loop: 32 pairs x 4 samples, pure VALU + broadcast ds_read ----
    v2f X[4], Y[4];
    #pragma unroll
    for (int k = 0; k < 4; ++k) {
        X[k] = (v2f){s[k].x, s[k].x};
        Y[k] = (v2f){s[k].y, s[k].y};
    }
    v2f acc[4] = {(v2f){0,0},(v2f){0,0},(v2f){0,0},(v2f){0,0}};

    const float4* cw = (const float4*)(coef + wv*64*6);   // wave's 32 pairs
    #pragma unroll 4
    for (int p = 0; p < 32; ++p) {
        const float4 q0 = cw[p*3 + 0];    // c0a c0b c1a c1b
        const float4 q1 = cw[p*3 + 1];    // c2a c2b c3a c3b
        const float4 q2 = cw[p*3 + 2];    // c4a c4b c5a c5b
        const v2f c0 = {q0.x, q0.y}, c1 = {q0.z, q0.w};
        const v2f c2 = {q1.x, q1.y}, c3 = {q1.z, q1.w};
        const v2f c4 = {q2.x, q2.y}, c5 = {q2.z, q2.w};
        #pragma unroll
        for (int k = 0; k < 4; ++k) {
            // q = c0 + x(c1 + c3x + c4y) + y(c2 + c5y): 5 pk_fma
            v2f u  = pkfma(c3, X[k], c1);
            u      = pkfma(c4, Y[k], u);
            v2f t3 = pkfma(c5, Y[k], c2);
            v2f v  = pkfma(u,  X[k], c0);
            v      = pkfma(t3, Y[k], v);
            const float ea = __builtin_amdgcn_exp2f(v.x);
            const float eb = __builtin_amdgcn_exp2f(v.y);
            acc[k] += (v2f){ea, eb};
        }
    }

    #pragma unroll
    for (int k = 0; k < 4; ++k)
        partial[wv*256 + 64*k + lane] = acc[k].x + acc[k].y;
    __syncthreads();

    if (t < 256) {
        float ssum = partial[t];
        #pragma unroll
        for (int i = 1; i < 16; ++i) ssum += partial[i*256 + t];
        out[base + t] = LN2 * (nlse + __builtin_amdgcn_logf(ssum));
    }
}

extern "C" void kernel_launch(void* const* d_in, const int* in_sizes, int n_in,
                              void* d_out, int out_size, void* d_ws, size_t ws_size,
                              hipStream_t stream) {
    const float* sample = (const float*)d_in[0];
    const float* mu     = (const float*)d_in[1];
    const float* A      = (const float*)d_in[2];
    const float* w      = (const float*)d_in[3];
    float* out = (float*)d_out;
    (void)in_sizes; (void)n_in; (void)out_size; (void)d_ws; (void)ws_size;

    gm_all<<<256, 1024, 0, stream>>>(sample, mu, A, w, out);
}

// Round 7
// 68.060 us; speedup vs baseline: 1.3132x; 1.0317x over previous
//
#include <hip/hip_runtime.h>
#include <math.h>

#define LOG2E 1.4426950408889634f
#define LN2   0.6931471805599453f

static constexpr int M = 1024;
static constexpr int N = 65536;

typedef short bf16x8 __attribute__((ext_vector_type(8)));
typedef float f32x4  __attribute__((ext_vector_type(4)));

__device__ inline float wave_max64(float v) {
    #pragma unroll
    for (int o = 32; o > 0; o >>= 1) v = fmaxf(v, __shfl_xor(v, o));
    return v;
}
__device__ inline float wave_sum64(float v) {
    #pragma unroll
    for (int o = 32; o > 0; o >>= 1) v += __shfl_xor(v, o);
    return v;
}

// truncate-to-bf16 pack: low half = bf16(a), high half = bf16(b)
__device__ inline unsigned pk2(float a, float b) {
    return (__float_as_uint(a) >> 16) | (__float_as_uint(b) & 0xFFFF0000u);
}
__device__ inline float truncbf(float f) {
    return __uint_as_float(__float_as_uint(f) & 0xFFFF0000u);
}

// Single kernel, 256 blocks x 1024 threads (1 block/CU, 4 waves/SIMD).
// v_ij = f_i . c_j is a K=6 GEMM -> offloaded to mfma_f32_16x16x32_bf16.
// Numerics: x centered at 0.5 (|terms| ~4x smaller) + full hi/lo bf16
// cross-product: K-blocks [ch,ch,cl,cl] x [fh,fl,fh,fl] = (ch+cl)(fh+fl)
// exactly; only split-truncation error remains (~1e-3 in v).
// Note any k-permutation applied identically to A- and B-frags leaves D
// invariant, so the operand k-mapping carries no correctness risk; comp-row
// permutations are absorbed by the sum over comps. Only D's col=lane&15
// (sample) mapping matters (m89-verified).
__global__ __launch_bounds__(1024)
void gm_all(const float* __restrict__ sample,
            const float* __restrict__ mu,
            const float* __restrict__ A,
            const float* __restrict__ w,
            float* __restrict__ out) {
    // 80 B/row stride (20 uints) -> conflict-free ds_read_b128
    __shared__ __align__(16) unsigned coefL[M*20];    // 80 KiB
    __shared__ __align__(16) unsigned featL[256*20];  // 20 KiB
    __shared__ float partial[16*256];                 // 16 KiB

    const int t    = threadIdx.x;
    const int lane = t & 63;
    const int wv   = t >> 6;
    const int base = blockIdx.x * 256;

    // ---------- stage features: thread t -> sample t>>2, k-slice t&3 ----------
    {
        const int s  = t >> 2;
        const int sl = t & 3;
        const float2 p = ((const float2*)sample)[base + s];
        const float x = p.x - 0.5f, y = p.y - 0.5f;
        const float f0 = 1.0f, f1 = x, f2 = y, f3 = x*x, f4 = x*y, f5 = y*y;
        const float g0 = f0 - truncbf(f0);            // exact 0
        const float g1 = f1 - truncbf(f1);
        const float g2 = f2 - truncbf(f2);
        const float g3 = f3 - truncbf(f3);
        const float g4 = f4 - truncbf(f4);
        const float g5 = f5 - truncbf(f5);
        const bool lo = (sl & 1);                     // slices 1,3 = lo part
        const float v0 = lo ? g0 : f0, v1 = lo ? g1 : f1, v2 = lo ? g2 : f2;
        const float v3 = lo ? g3 : f3, v4 = lo ? g4 : f4, v5 = lo ? g5 : f5;
        uint4 q;
        q.x = pk2(v0, v1); q.y = pk2(v2, v3); q.z = pk2(v4, v5); q.w = 0u;
        *(uint4*)&featL[s*20 + sl*4] = q;
    }

    // ---------- stage coefs: thread t -> comp t ----------
    {
        const float4 a4 = ((const float4*)A)[t];      // A00,A01,A10,A11
        const float2 m2 = ((const float2*)mu)[t];
        const float  wt = w[t];
        const float g00 = a4.x*a4.x + a4.y*a4.y;
        const float g01 = a4.x*a4.z + a4.y*a4.w;
        const float g11 = a4.z*a4.z + a4.w*a4.w;
        const float gm0 = g00*m2.x + g01*m2.y;
        const float gm1 = g01*m2.x + g11*m2.y;
        const float mGm = gm0*m2.x + gm1*m2.y;
        const float det = g00*g11 - g01*g01;
        const float t2  = wt*LOG2E + 0.5f*__builtin_amdgcn_logf(det);
        // original-basis coefs (v = c0o + c1o x + c2o y + c3 x^2 + c4 xy + c5 y^2)
        const float c0o = t2 - LOG2E*mGm;
        const float c1o = LOG2E*2.0f*gm0;
        const float c2o = LOG2E*2.0f*gm1;
        const float c3  = -LOG2E*g00;
        const float c4  = -LOG2E*2.0f*g01;
        const float c5  = -LOG2E*g11;
        // shift to x' = x-0.5 basis
        const float c1 = c1o + c3 + 0.5f*c4;
        const float c2 = c2o + c5 + 0.5f*c4;
        const float c0 = c0o + 0.5f*(c1o + c2o) + 0.25f*(c3 + c4 + c5);
        // hi/lo split (truncation; lo captures remainder)
        const unsigned h0 = pk2(c0, c1), h1 = pk2(c2, c3), h2 = pk2(c4, c5);
        const float l0 = c0 - truncbf(c0), l1 = c1 - truncbf(c1);
        const float l2 = c2 - truncbf(c2), l3 = c3 - truncbf(c3);
        const float l4 = c4 - truncbf(c4), l5 = c5 - truncbf(c5);
        const unsigned o0 = pk2(l0, l1), o1 = pk2(l2, l3), o2 = pk2(l4, l5);
        const uint4 hi4 = {h0, h1, h2, 0u};
        const uint4 lo4 = {o0, o1, o2, 0u};
        // k-slices: 0,1 = ch (pairs with fh,fl); 2,3 = cl (pairs with fh,fl)
        *(uint4*)&coefL[t*20 + 0]  = hi4;
        *(uint4*)&coefL[t*20 + 4]  = hi4;
        *(uint4*)&coefL[t*20 + 8]  = lo4;
        *(uint4*)&coefL[t*20 + 12] = lo4;
    }

    // ---------- w logsumexp: waves 0-3 only (their t<256 use nlse) ----------
    float nlse = 0.0f;
    if (wv < 4) {
        float4 wq[4];
        #pragma unroll
        for (int i = 0; i < 4; ++i)
            wq[i] = ((const float4*)w)[lane + 64*i];
        float wmax = wq[0].x;
        #pragma unroll
        for (int i = 0; i < 4; ++i) {
            wmax = fmaxf(wmax, wq[i].x); wmax = fmaxf(wmax, wq[i].y);
            wmax = fmaxf(wmax, wq[i].z); wmax = fmaxf(wmax, wq[i].w);
        }
        wmax = wave_max64(wmax);
        float sw = 0.0f;
        #pragma unroll
        for (int i = 0; i < 4; ++i) {
            sw += __builtin_amdgcn_exp2f((wq[i].x - wmax)*LOG2E);
            sw += __builtin_amdgcn_exp2f((wq[i].y - wmax)*LOG2E);
            sw += __builtin_amdgcn_exp2f((wq[i].z - wmax)*LOG2E);
            sw += __builtin_amdgcn_exp2f((wq[i].w - wmax)*LOG2E);
        }
        sw = wave_sum64(sw);
        nlse = -(wmax*LOG2E + __builtin_amdgcn_logf(sw));
    }

    __syncthreads();   // features are cross-wave; coefs are wave-local

    // ---------- main: per wave, 4 comp-tiles x 16 sample-tiles ----------
    const int l15 = lane & 15;        // A row (comp) / B,D col (sample)
    const int ksl = lane >> 4;        // k-slice
    bf16x8 aA[4];
    #pragma unroll
    for (int ct = 0; ct < 4; ++ct)
        aA[ct] = *(const bf16x8*)&coefL[(wv*64 + ct*16 + l15)*20 + ksl*4];

    const f32x4 zero4 = {0.0f, 0.0f, 0.0f, 0.0f};
    for (int st = 0; st < 16; ++st) {
        const bf16x8 bB = *(const bf16x8*)&featL[(st*16 + l15)*20 + ksl*4];
        f32x4 d0 = __builtin_amdgcn_mfma_f32_16x16x32_bf16(aA[0], bB, zero4, 0, 0, 0);
        f32x4 d1 = __builtin_amdgcn_mfma_f32_16x16x32_bf16(aA[1], bB, zero4, 0, 0, 0);
        f32x4 d2 = __builtin_amdgcn_mfma_f32_16x16x32_bf16(aA[2], bB, zero4, 0, 0, 0);
        f32x4 d3 = __builtin_amdgcn_mfma_f32_16x16x32_bf16(aA[3], bB, zero4, 0, 0, 0);
        float s0 = (__builtin_amdgcn_exp2f(d0[0]) + __builtin_amdgcn_exp2f(d0[1]))
                 + (__builtin_amdgcn_exp2f(d0[2]) + __builtin_amdgcn_exp2f(d0[3]));
        float s1 = (__builtin_amdgcn_exp2f(d1[0]) + __builtin_amdgcn_exp2f(d1[1]))
                 + (__builtin_amdgcn_exp2f(d1[2]) + __builtin_amdgcn_exp2f(d1[3]));
        float s2 = (__builtin_amdgcn_exp2f(d2[0]) + __builtin_amdgcn_exp2f(d2[1]))
                 + (__builtin_amdgcn_exp2f(d2[2]) + __builtin_amdgcn_exp2f(d2[3]));
        float s3 = (__builtin_amdgcn_exp2f(d3[0]) + __builtin_amdgcn_exp2f(d3[1]))
                 + (__builtin_amdgcn_exp2f(d3[2]) + __builtin_amdgcn_exp2f(d3[3]));
        float s = (s0 + s1) + (s2 + s3);   // this lane: 16 comps, 1 sample
        s += __shfl_xor(s, 16);            // sum the 4 ksl row-groups
        s += __shfl_xor(s, 32);
        if (ksl == 0) partial[wv*256 + st*16 + l15] = s;
    }

    __syncthreads();

    if (t < 256) {
        float ssum = partial[t];
        #pragma unroll
        for (int i = 1; i < 16; ++i) ssum += partial[i*256 + t];
        out[base + t] = LN2 * (nlse + __builtin_amdgcn_logf(ssum));
    }
}

extern "C" void kernel_launch(void* const* d_in, const int* in_sizes, int n_in,
                              void* d_out, int out_size, void* d_ws, size_t ws_size,
                              hipStream_t stream) {
    const float* sample = (const float*)d_in[0];
    const float* mu     = (const float*)d_in[1];
    const float* A      = (const float*)d_in[2];
    const float* w      = (const float*)d_in[3];
    float* out = (float*)d_out;
    (void)in_sizes; (void)n_in; (void)out_size; (void)d_ws; (void)ws_size;

    gm_all<<<256, 1024, 0, stream>>>(sample, mu, A, w, out);
}